// Round 3
// baseline (208.366 us; speedup 1.0000x reference)
//
#include <hip/hip_runtime.h>
#include <hip/hip_bf16.h>

#define B 16
#define N 20000
#define F 512
#define K 200
#define ROWS (B*N)
#define CH 10      // gather chunks per batch
#define RPC 20     // rows per chunk (CH*RPC == K)
#define CAP 2048   // top-k candidate capacity

__device__ __forceinline__ unsigned key32(float s){
    unsigned u = __float_as_uint(s);
    return (u & 0x80000000u) ? ~u : (u | 0x80000000u);
}
__device__ __forceinline__ float inv_key32(unsigned k){
    unsigned u = (k & 0x80000000u) ? (k & 0x7FFFFFFFu) : ~k;
    return __uint_as_float(u);
}
__device__ __forceinline__ unsigned long long key64(double s){
    unsigned long long u = (unsigned long long)__double_as_longlong(s);
    return (u >> 63) ? ~u : (u | 0x8000000000000000ull);
}

// ---------------- K0: init per-batch max keys ----------------
__global__ void k_init(unsigned* bmax){
    if (threadIdx.x < B) bmax[threadIdx.x] = 0u;
}

// ---------------- K1: scores (f64 dot) + per-batch max ----------------
__global__ __launch_bounds__(256) void k_scores(const float* __restrict__ x,
                                                const float* __restrict__ w,
                                                double* __restrict__ sc,
                                                unsigned* __restrict__ bmax,
                                                int rows_per_block){
    __shared__ unsigned lmax[B];
    int t = threadIdx.x;
    if (t < B) lmax[t] = 0u;
    __syncthreads();
    int lane = t & 63, wid = t >> 6;

    const float4* w4 = (const float4*)w;
    float4 ka = w4[lane*2], kb = w4[lane*2+1];
    double k0=ka.x,k1=ka.y,k2=ka.z,k3=ka.w,k4=kb.x,k5=kb.y,k6=kb.z,k7=kb.w;

    long seg = (long)blockIdx.x * rows_per_block;
    long end = seg + rows_per_block; if (end > (long)ROWS) end = ROWS;
    for (long r = seg + wid; r < end; r += 4){
        const float4* rp = (const float4*)(x + r*(long)F);
        float4 a = rp[lane*2], b2 = rp[lane*2+1];
        double acc = (double)a.x*k0 + (double)a.y*k1 + (double)a.z*k2 + (double)a.w*k3
                   + (double)b2.x*k4 + (double)b2.y*k5 + (double)b2.z*k6 + (double)b2.w*k7;
        #pragma unroll
        for (int m=1; m<64; m<<=1) acc += __shfl_xor(acc, m, 64);
        if (lane == 0){
            sc[r] = acc;
            int b = (int)(r / N);
            atomicMax(&lmax[b], key32((float)acc));
        }
    }
    __syncthreads();
    if (t < B && lmax[t]) atomicMax(&bmax[t], lmax[t]);
}

// ---------------- K2: per-batch sum of exp ----------------
__global__ __launch_bounds__(1024) void k_sumexp(const double* __restrict__ sc,
                                                 const unsigned* __restrict__ bmax,
                                                 double* __restrict__ bsum){
    __shared__ double red[1024];
    int b = blockIdx.x, t = threadIdx.x;
    float m = inv_key32(bmax[b]);
    const double* s = sc + (long)b*N;
    double acc = 0.0;
    for (int n = t; n < N; n += 1024) acc += (double)expf((float)s[n] - m);
    red[t] = acc; __syncthreads();
    for (int o = 512; o > 0; o >>= 1){ if (t < o) red[t] += red[t+o]; __syncthreads(); }
    if (t == 0) bsum[b] = red[0];
}

// ---------------- K4: probs write + exact top-k + sel softmax ----------------
__global__ __launch_bounds__(1024) void k_topk(const double* __restrict__ sc,
                                               const unsigned* __restrict__ bmax,
                                               const double* __restrict__ bsum,
                                               float* __restrict__ out,
                                               int* __restrict__ selidx,
                                               float* __restrict__ selw){
    __shared__ unsigned hist[2048];
    __shared__ unsigned long long ckey[CAP];
    __shared__ int cidx[CAP];
    __shared__ float selp[256];
    __shared__ float fred[1024];
    __shared__ int ccount, pivot;

    int b = blockIdx.x, t = threadIdx.x;
    const double* s = sc + (long)b*N;
    float m = inv_key32(bmax[b]);
    float sumf = (float)bsum[b];

    hist[t] = 0u; hist[t+1024] = 0u;
    if (t == 0) ccount = 0;
    __syncthreads();

    // pass A: histogram of 11-bit f32 keys + probs output (f32)
    float* probs_out = out + B*K + (long)b*N;
    for (int n = t; n < N; n += 1024){
        float sf = (float)s[n];
        atomicAdd(&hist[key32(sf)>>21], 1u);
        probs_out[n] = expf(sf - m) / sumf;
    }
    __syncthreads();

    // suffix sums over 2048 bins (count of elements with bin >= t)
    for (int off = 1; off < 2048; off <<= 1){
        unsigned v0 = hist[t]      + ((t+off)      < 2048 ? hist[t+off]      : 0u);
        unsigned v1 = hist[t+1024] + ((t+1024+off) < 2048 ? hist[t+1024+off] : 0u);
        __syncthreads();
        hist[t] = v0; hist[t+1024] = v1;
        __syncthreads();
    }
    // pivot = max bin with suffix count >= K
    for (int tt = t; tt < 2048; tt += 1024){
        if (hist[tt] >= K && (tt == 2047 || hist[tt+1] < K)) pivot = tt;
    }
    __syncthreads();
    int P = pivot;

    // pass B: compact candidates (bin >= P)
    for (int n = t; n < N; n += 1024){
        float sf = (float)s[n];
        if ((int)(key32(sf)>>21) >= P){
            int pos = atomicAdd(&ccount, 1);
            if (pos < CAP){ ckey[pos] = key64(s[n]); cidx[pos] = n; }
        }
    }
    __syncthreads();
    int C = ccount; if (C > CAP) C = CAP;

    // pass C: exact rank (f64 value desc, index asc) — matches lax.top_k ties
    for (int i = t; i < C; i += 1024){
        unsigned long long ki = ckey[i]; int xi = cidx[i];
        int rank = 0;
        for (int j = 0; j < C; j++){
            unsigned long long kj = ckey[j];
            rank += (kj > ki) || (kj == ki && cidx[j] < xi);
        }
        if (rank < K){
            out[b*K + rank] = (float)xi;
            selidx[b*K + rank] = xi;
            float sf = (float)s[xi];
            selp[rank] = expf(sf - m) / sumf;
        }
    }
    __syncthreads();

    // sel re-softmax over the K selected probs
    float v = (t < K) ? selp[t] : -3.0e38f;
    fred[t] = v; __syncthreads();
    for (int o = 512; o > 0; o >>= 1){ if (t < o) fred[t] = fmaxf(fred[t], fred[t+o]); __syncthreads(); }
    float m2 = fred[0]; __syncthreads();
    float wv = (t < K) ? expf(selp[t] - m2) : 0.0f;
    fred[t] = wv; __syncthreads();
    for (int o = 512; o > 0; o >>= 1){ if (t < o) fred[t] += fred[t+o]; __syncthreads(); }
    float sw = fred[0];
    if (t < K) selw[b*K + t] = wv / sw;
}

// ---------------- K5a: weighted gather into per-chunk partials ----------------
__global__ __launch_bounds__(128) void k_gather(const float* __restrict__ x,
                                                const int* __restrict__ selidx,
                                                const float* __restrict__ selw,
                                                float* __restrict__ partial){
    int b = blockIdx.x / CH, ch = blockIdx.x % CH;
    int t = threadIdx.x;
    float4 acc = {0.f,0.f,0.f,0.f};
    for (int i = 0; i < RPC; i++){
        int s = b*K + ch*RPC + i;
        int idx = selidx[s];
        float wv = selw[s];
        const float4* rp = (const float4*)(x + ((long)b*N + idx)*(long)F);
        float4 vv = rp[t];
        acc.x += wv*vv.x; acc.y += wv*vv.y; acc.z += wv*vv.z; acc.w += wv*vv.w;
    }
    float4* pp = (float4*)(partial + (long)(b*CH + ch)*F);
    pp[t] = acc;
}

// ---------------- K5b: final sum + global L2 normalize ----------------
__global__ __launch_bounds__(1024) void k_final(const float* __restrict__ partial,
                                                float* __restrict__ out_emb){
    __shared__ double red[1024];
    int t = threadIdx.x;
    float mine[8];
    double ssq = 0.0;
    #pragma unroll
    for (int k = 0; k < 8; k++){
        int i = t + k*1024;            // B*F == 8192 exactly
        int b = i >> 9, f = i & 511;
        float sv = 0.f;
        for (int c = 0; c < CH; c++) sv += partial[(b*CH + c)*F + f];
        mine[k] = sv;
        ssq += (double)sv * sv;
    }
    red[t] = ssq; __syncthreads();
    for (int o = 512; o > 0; o >>= 1){ if (t < o) red[t] += red[t+o]; __syncthreads(); }
    float scale = rsqrtf(fmaxf((float)red[0], 1e-12f));
    #pragma unroll
    for (int k = 0; k < 8; k++){
        int i = t + k*1024;
        out_emb[i] = mine[k] * scale;
    }
}

extern "C" void kernel_launch(void* const* d_in, const int* in_sizes, int n_in,
                              void* d_out, int out_size, void* d_ws, size_t ws_size,
                              hipStream_t stream){
    const float* x = (const float*)d_in[0];
    const float* w = (const float*)d_in[1];
    float* out = (float*)d_out;
    char* ws = (char*)d_ws;

    double*   sc      = (double*)(ws);               // 320000*8 = 2,560,000
    unsigned* bmax    = (unsigned*)(ws + 2560000);   // 16*4
    double*   bsum    = (double*)(ws + 2560064);     // 16*8
    int*      selidx  = (int*)(ws + 2560192);        // 3200*4
    float*    selw    = (float*)(ws + 2572992);      // 3200*4
    float*    partial = (float*)(ws + 2585792);      // 16*10*512*4 = 327,680

    k_init<<<dim3(1), dim3(64), 0, stream>>>(bmax);

    const int grid1 = 2048;
    const int rpb = (ROWS + grid1 - 1) / grid1;
    k_scores<<<dim3(grid1), dim3(256), 0, stream>>>(x, w, sc, bmax, rpb);

    k_sumexp<<<dim3(B), dim3(1024), 0, stream>>>(sc, bmax, bsum);

    k_topk<<<dim3(B), dim3(1024), 0, stream>>>(sc, bmax, bsum, out, selidx, selw);

    k_gather<<<dim3(B*CH), dim3(128), 0, stream>>>(x, selidx, selw, partial);

    k_final<<<dim3(1), dim3(1024), 0, stream>>>(partial, out + B*K + (long)B*N);
}

// Round 4
// 200.955 us; speedup vs baseline: 1.0369x; 1.0369x over previous
//
#include <hip/hip_runtime.h>
#include <hip/hip_bf16.h>

#define B 16
#define N 20000
#define F 512
#define K 200
#define ROWS (B*N)
#define GRID1 2000          // score blocks
#define RPB 160             // rows per score block (2000*160 == ROWS, 125 blocks/batch)
#define PSB 125             // partial-sum blocks per batch
#define CAP 2048            // top-k candidate capacity

__device__ __forceinline__ unsigned key32(float s){
    unsigned u = __float_as_uint(s);
    return (u & 0x80000000u) ? ~u : (u | 0x80000000u);
}
__device__ __forceinline__ unsigned long long key64(double s){
    unsigned long long u = (unsigned long long)__double_as_longlong(s);
    return (u >> 63) ? ~u : (u | 0x8000000000000000ull);
}
__device__ __forceinline__ double inv_key64(unsigned long long k){
    unsigned long long u = (k >> 63) ? (k & 0x7FFFFFFFFFFFFFFFull) : ~k;
    return __longlong_as_double((long long)u);
}

// ---------------- K1: scores (f64 dot, software-pipelined) + per-block sum(exp) ----------------
__global__ __launch_bounds__(256) void k_scores(const float* __restrict__ x,
                                                const float* __restrict__ w,
                                                double* __restrict__ sc,
                                                double* __restrict__ psum){
    __shared__ double wsum[4];
    int t = threadIdx.x, lane = t & 63, wid = t >> 6;

    const float4* w4 = (const float4*)w;
    float4 ka = w4[lane*2], kb = w4[lane*2+1];
    double k0=ka.x,k1=ka.y,k2=ka.z,k3=ka.w,k4=kb.x,k5=kb.y,k6=kb.z,k7=kb.w;

    const float4* xp = (const float4*)x;
    long seg = (long)blockIdx.x * RPB;
    long r0 = seg + wid;                 // rows r0, r0+4, ..., r0+156 (40 rows, 20 pairs)
    double esum = 0.0;

    // prologue: pair 0 (rows r0, r0+4)
    float4 a0 = xp[r0*128 + lane*2],     a1 = xp[r0*128 + lane*2 + 1];
    float4 b0 = xp[(r0+4)*128 + lane*2], b1 = xp[(r0+4)*128 + lane*2 + 1];

    #pragma unroll 1
    for (int it = 0; it < 20; ++it){
        long r = r0 + (long)it*8;
        float4 na0=a0, na1=a1, nb0=b0, nb1=b1;
        if (it < 19){
            long nr = r + 8;
            na0 = xp[nr*128 + lane*2];     na1 = xp[nr*128 + lane*2 + 1];
            nb0 = xp[(nr+4)*128 + lane*2]; nb1 = xp[(nr+4)*128 + lane*2 + 1];
        }
        double accA = (double)a0.x*k0 + (double)a0.y*k1 + (double)a0.z*k2 + (double)a0.w*k3
                    + (double)a1.x*k4 + (double)a1.y*k5 + (double)a1.z*k6 + (double)a1.w*k7;
        double accB = (double)b0.x*k0 + (double)b0.y*k1 + (double)b0.z*k2 + (double)b0.w*k3
                    + (double)b1.x*k4 + (double)b1.y*k5 + (double)b1.z*k6 + (double)b1.w*k7;
        #pragma unroll
        for (int m=1; m<64; m<<=1){
            accA += __shfl_xor(accA, m, 64);
            accB += __shfl_xor(accB, m, 64);
        }
        if (lane == 0){
            sc[r]   = accA;
            sc[r+4] = accB;
            esum += (double)expf((float)accA) + (double)expf((float)accB);
        }
        a0=na0; a1=na1; b0=nb0; b1=nb1;
    }
    if (lane == 0) wsum[wid] = esum;
    __syncthreads();
    if (t == 0) psum[blockIdx.x] = ((wsum[0]+wsum[1]) + (wsum[2]+wsum[3]));
}

// ---------------- K2: fused probs + exact top-k + sel softmax + gather ----------------
__global__ __launch_bounds__(1024) void k_fused(const double* __restrict__ sc,
                                                const double* __restrict__ psum,
                                                const float* __restrict__ x,
                                                float* __restrict__ out,
                                                float* __restrict__ summed){
    __shared__ unsigned hist[2048];
    __shared__ unsigned long long ckey[CAP];
    __shared__ int cidx[CAP];
    __shared__ float selp[256];
    __shared__ int selidx_s[256];
    __shared__ float selw_s[256];
    __shared__ float fred[1024];
    __shared__ double dred[256];
    __shared__ float4 gacc[8][128];
    __shared__ int ccount, pivot;

    int b = blockIdx.x, t = threadIdx.x;
    const double* s = sc + (long)b*N;

    // deterministic Σexp: fixed tree over 125 per-block partials
    if (t < 256) dred[t] = (t < PSB) ? psum[b*PSB + t] : 0.0;
    hist[t] = 0u; hist[t+1024] = 0u;
    if (t == 0) ccount = 0;
    __syncthreads();
    for (int o = 128; o > 0; o >>= 1){ if (t < o) dred[t] += dred[t+o]; __syncthreads(); }
    float invsum = 1.0f / (float)dred[0];

    // pass A: histogram of 11-bit f32 keys + probs output (f32)
    float* probs_out = out + B*K + (long)b*N;
    for (int n = t; n < N; n += 1024){
        float sf = (float)s[n];
        atomicAdd(&hist[key32(sf)>>21], 1u);
        probs_out[n] = expf(sf) * invsum;
    }
    __syncthreads();

    // suffix sums over 2048 bins (count of elements with bin >= t)
    for (int off = 1; off < 2048; off <<= 1){
        unsigned v0 = hist[t]      + ((t+off)      < 2048 ? hist[t+off]      : 0u);
        unsigned v1 = hist[t+1024] + ((t+1024+off) < 2048 ? hist[t+1024+off] : 0u);
        __syncthreads();
        hist[t] = v0; hist[t+1024] = v1;
        __syncthreads();
    }
    // pivot = max bin with suffix count >= K
    for (int tt = t; tt < 2048; tt += 1024){
        if (hist[tt] >= K && (tt == 2047 || hist[tt+1] < K)) pivot = tt;
    }
    __syncthreads();
    int P = pivot;

    // pass B: compact candidates (bin >= P)
    for (int n = t; n < N; n += 1024){
        double sv = s[n];
        float sf = (float)sv;
        if ((int)(key32(sf)>>21) >= P){
            int pos = atomicAdd(&ccount, 1);
            if (pos < CAP){ ckey[pos] = key64(sv); cidx[pos] = n; }
        }
    }
    __syncthreads();
    int C = ccount; if (C > CAP) C = CAP;

    // pass C: exact rank (f64 value desc, index asc) — matches lax.top_k ties
    for (int i = t; i < C; i += 1024){
        unsigned long long ki = ckey[i]; int xi = cidx[i];
        int rank = 0;
        for (int j = 0; j < C; j++){
            unsigned long long kj = ckey[j];
            rank += (kj > ki) || (kj == ki && cidx[j] < xi);
        }
        if (rank < K){
            out[b*K + rank] = (float)xi;
            selidx_s[rank] = xi;
            selp[rank] = expf((float)inv_key64(ki)) * invsum;
        }
    }
    __syncthreads();

    // sel re-softmax over the K selected probs
    float v = (t < K) ? selp[t] : -3.0e38f;
    fred[t] = v; __syncthreads();
    for (int o = 512; o > 0; o >>= 1){ if (t < o) fred[t] = fmaxf(fred[t], fred[t+o]); __syncthreads(); }
    float m2 = fred[0]; __syncthreads();
    float wv = (t < K) ? expf(selp[t] - m2) : 0.0f;
    fred[t] = wv; __syncthreads();
    for (int o = 512; o > 0; o >>= 1){ if (t < o) fred[t] += fred[t+o]; __syncthreads(); }
    float sw = fred[0];
    if (t < K) selw_s[t] = wv / sw;
    __syncthreads();

    // weighted gather: 8 row-groups x 128 f4-columns, deterministic tree combine
    int g = t >> 7, q = t & 127;
    float4 acc = {0.f,0.f,0.f,0.f};
    for (int i = g; i < K; i += 8){
        int idx = selidx_s[i];
        float wvi = selw_s[i];
        const float4* rp = (const float4*)(x + ((long)b*N + idx)*(long)F);
        float4 vv = rp[q];
        acc.x += wvi*vv.x; acc.y += wvi*vv.y; acc.z += wvi*vv.z; acc.w += wvi*vv.w;
    }
    gacc[g][q] = acc; __syncthreads();
    if (g < 4){
        float4 o4 = gacc[g+4][q];
        gacc[g][q].x += o4.x; gacc[g][q].y += o4.y; gacc[g][q].z += o4.z; gacc[g][q].w += o4.w;
    }
    __syncthreads();
    if (g < 2){
        float4 o4 = gacc[g+2][q];
        gacc[g][q].x += o4.x; gacc[g][q].y += o4.y; gacc[g][q].z += o4.z; gacc[g][q].w += o4.w;
    }
    __syncthreads();
    if (g == 0){
        float4 o4 = gacc[1][q];
        float4 r4 = gacc[0][q];
        r4.x += o4.x; r4.y += o4.y; r4.z += o4.z; r4.w += o4.w;
        float4* sp = (float4*)(summed + b*F);
        sp[q] = r4;
    }
}

// ---------------- K3: global L2 normalize ----------------
__global__ __launch_bounds__(1024) void k_norm(const float* __restrict__ summed,
                                               float* __restrict__ out_emb){
    __shared__ double red[1024];
    int t = threadIdx.x;
    float mine[8];
    double ssq = 0.0;
    #pragma unroll
    for (int k = 0; k < 8; k++){
        int i = t + k*1024;            // B*F == 8192 exactly
        float sv = summed[i];
        mine[k] = sv;
        ssq += (double)sv * sv;
    }
    red[t] = ssq; __syncthreads();
    for (int o = 512; o > 0; o >>= 1){ if (t < o) red[t] += red[t+o]; __syncthreads(); }
    float scale = rsqrtf(fmaxf((float)red[0], 1e-12f));
    #pragma unroll
    for (int k = 0; k < 8; k++){
        int i = t + k*1024;
        out_emb[i] = mine[k] * scale;
    }
}

extern "C" void kernel_launch(void* const* d_in, const int* in_sizes, int n_in,
                              void* d_out, int out_size, void* d_ws, size_t ws_size,
                              hipStream_t stream){
    const float* x = (const float*)d_in[0];
    const float* w = (const float*)d_in[1];
    float* out = (float*)d_out;
    char* ws = (char*)d_ws;

    double* sc     = (double*)(ws);                 // 320000*8 = 2,560,000
    double* psum   = (double*)(ws + 2560000);       // 2000*8   = 16,000
    float*  summed = (float*)(ws + 2576000);        // 16*512*4 = 32,768

    k_scores<<<dim3(GRID1), dim3(256), 0, stream>>>(x, w, sc, psum);
    k_fused<<<dim3(B), dim3(1024), 0, stream>>>(sc, psum, x, out, summed);
    k_norm<<<dim3(1), dim3(1024), 0, stream>>>(summed, out + B*K + (long)B*N);
}